// Round 1
// baseline (64.446 us; speedup 1.0000x reference)
//
#include <hip/hip_runtime.h>

// Elastic wave time step (seistorch _time_step), B=4, NZ=NX=1024, f32.
// Two kernels: stress update then velocity update (velocity needs neighbor
// values of the NEW stresses). Circular roll semantics -> wrap with &(N-1).

constexpr int Bn = 4, NZ = 1024, NX = 1024;
constexpr int NQ = NX / 4;            // float4 quads per row = 256
constexpr int PLANE = NZ * NX;
constexpr int NPTS = Bn * PLANE;      // per-field elements
constexpr int NQTOT = Bn * NZ * NQ;   // total quads = 2^20

__global__ __launch_bounds__(256) void stress_kernel(
    const float* __restrict__ vp, const float* __restrict__ vs,
    const float* __restrict__ rho, const float* __restrict__ vx,
    const float* __restrict__ vz, const float* __restrict__ txx,
    const float* __restrict__ tzz, const float* __restrict__ txz,
    const float* __restrict__ dtp, const float* __restrict__ hp,
    const float* __restrict__ dpml,
    float* __restrict__ y_txx, float* __restrict__ y_tzz,
    float* __restrict__ y_txz)
{
    int q = blockIdx.x * blockDim.x + threadIdx.x;
    if (q >= NQTOT) return;
    int xq = q & (NQ - 1);
    int z  = (q >> 8) & (NZ - 1);
    int b  = q >> 18;
    int x0 = xq * 4;
    int zp = (z + 1) & (NZ - 1);
    int base   = b * PLANE + z * NX + x0;
    int basezp = b * PLANE + zp * NX + x0;
    int mbase  = z * NX + x0;

    float4 vxc  = *(const float4*)(vx + base);
    float4 vxzp = *(const float4*)(vx + basezp);
    float  vxm1 = vx[b * PLANE + z * NX + ((x0 - 1) & (NX - 1))];
    float4 vzc  = *(const float4*)(vz + base);
    float4 vzzp = *(const float4*)(vz + basezp);
    float  vzp4 = vz[b * PLANE + z * NX + ((x0 + 4) & (NX - 1))];
    float4 txxc = *(const float4*)(txx + base);
    float4 tzzc = *(const float4*)(tzz + base);
    float4 txzc = *(const float4*)(txz + base);
    float4 vpv  = *(const float4*)(vp + mbase);
    float4 vsv  = *(const float4*)(vs + mbase);
    float4 rhv  = *(const float4*)(rho + mbase);
    float4 dv   = *(const float4*)(dpml + mbase);

    float dt = dtp[0], h = hp[0];
    float dth = dt / h;

    float fvx[5]  = {vxm1, vxc.x, vxc.y, vxc.z, vxc.w};
    float fvz[5]  = {vzc.x, vzc.y, vzc.z, vzc.w, vzp4};
    float fvxzp[4] = {vxzp.x, vxzp.y, vxzp.z, vxzp.w};
    float fvzzp[4] = {vzzp.x, vzzp.y, vzzp.z, vzzp.w};
    float ftxx[4] = {txxc.x, txxc.y, txxc.z, txxc.w};
    float ftzz[4] = {tzzc.x, tzzc.y, tzzc.z, tzzc.w};
    float ftxz[4] = {txzc.x, txzc.y, txzc.z, txzc.w};
    float fvp[4]  = {vpv.x, vpv.y, vpv.z, vpv.w};
    float fvs[4]  = {vsv.x, vsv.y, vsv.z, vsv.w};
    float frh[4]  = {rhv.x, rhv.y, rhv.z, rhv.w};
    float fd[4]   = {dv.x, dv.y, dv.z, dv.w};

    float o_txx[4], o_tzz[4], o_txz[4];
#pragma unroll
    for (int i = 0; i < 4; ++i) {
        float lam = frh[i] * (fvp[i] * fvp[i] - 2.0f * fvs[i] * fvs[i]);
        float mu  = frh[i] * fvs[i] * fvs[i];
        float vx_x = fvx[i + 1] - fvx[i];        // vx[x] - vx[x-1]
        float vz_z = fvzzp[i] - fvz[i];          // vz[z+1] - vz[z]
        float vx_z = fvxzp[i] - fvx[i + 1];      // vx[z+1] - vx[z]
        float vz_x = fvz[i + 1] - fvz[i];        // vz[x+1] - vz[x]
        float c   = 0.5f * dt * fd[i];
        float inv = 1.0f / (1.0f + c);
        float omc = 1.0f - c;
        float lp2m = lam + 2.0f * mu;
        o_txx[i] = inv * (dth * (lp2m * vx_x + lam * vz_z) + omc * ftxx[i]);
        o_tzz[i] = inv * (dth * (lp2m * vz_z + lam * vx_x) + omc * ftzz[i]);
        o_txz[i] = inv * (dth * mu * (vz_x + vx_z) + omc * ftxz[i]);
    }
    *(float4*)(y_txx + base) = make_float4(o_txx[0], o_txx[1], o_txx[2], o_txx[3]);
    *(float4*)(y_tzz + base) = make_float4(o_tzz[0], o_tzz[1], o_tzz[2], o_tzz[3]);
    *(float4*)(y_txz + base) = make_float4(o_txz[0], o_txz[1], o_txz[2], o_txz[3]);
}

__global__ __launch_bounds__(256) void vel_kernel(
    const float* __restrict__ rho, const float* __restrict__ vx,
    const float* __restrict__ vz,
    const float* __restrict__ y_txx, const float* __restrict__ y_tzz,
    const float* __restrict__ y_txz,
    const float* __restrict__ dtp, const float* __restrict__ hp,
    const float* __restrict__ dpml,
    float* __restrict__ y_vx, float* __restrict__ y_vz)
{
    int q = blockIdx.x * blockDim.x + threadIdx.x;
    if (q >= NQTOT) return;
    int xq = q & (NQ - 1);
    int z  = (q >> 8) & (NZ - 1);
    int b  = q >> 18;
    int x0 = xq * 4;
    int zm = (z - 1) & (NZ - 1);
    int base   = b * PLANE + z * NX + x0;
    int basezm = b * PLANE + zm * NX + x0;
    int mbase  = z * NX + x0;

    float4 txxc  = *(const float4*)(y_txx + base);
    float  txxp4 = y_txx[b * PLANE + z * NX + ((x0 + 4) & (NX - 1))];
    float4 txzc  = *(const float4*)(y_txz + base);
    float4 txzzm = *(const float4*)(y_txz + basezm);
    float  txzm1 = y_txz[b * PLANE + z * NX + ((x0 - 1) & (NX - 1))];
    float4 tzzc  = *(const float4*)(y_tzz + base);
    float4 tzzzm = *(const float4*)(y_tzz + basezm);
    float4 vxc   = *(const float4*)(vx + base);
    float4 vzc   = *(const float4*)(vz + base);
    float4 rhv   = *(const float4*)(rho + mbase);
    float4 dv    = *(const float4*)(dpml + mbase);

    float dt = dtp[0], h = hp[0];
    float dth = dt / h;

    float ftxx[5]  = {txxc.x, txxc.y, txxc.z, txxc.w, txxp4};
    float ftxz[5]  = {txzm1, txzc.x, txzc.y, txzc.z, txzc.w};
    float ftzz[4]  = {tzzc.x, tzzc.y, tzzc.z, tzzc.w};
    float ftxzzm[4] = {txzzm.x, txzzm.y, txzzm.z, txzzm.w};
    float ftzzzm[4] = {tzzzm.x, tzzzm.y, tzzzm.z, tzzzm.w};
    float fvx[4] = {vxc.x, vxc.y, vxc.z, vxc.w};
    float fvz[4] = {vzc.x, vzc.y, vzc.z, vzc.w};
    float frh[4] = {rhv.x, rhv.y, rhv.z, rhv.w};
    float fd[4]  = {dv.x, dv.y, dv.z, dv.w};

    float o_vx[4], o_vz[4];
#pragma unroll
    for (int i = 0; i < 4; ++i) {
        float txx_x = ftxx[i + 1] - ftxx[i];        // y_txx[x+1]-y_txx[x]
        float txz_z = ftxz[i + 1] - ftxzzm[i];      // y_txz[z]-y_txz[z-1]
        float tzz_z = ftzz[i] - ftzzzm[i];          // y_tzz[z]-y_tzz[z-1]
        float txz_x = ftxz[i + 1] - ftxz[i];        // y_txz[x]-y_txz[x-1]
        float c   = 0.5f * dt * fd[i];
        float inv = 1.0f / (1.0f + c);
        float omc = 1.0f - c;
        float s = dth / frh[i];
        o_vx[i] = inv * (s * (txx_x + txz_z) + omc * fvx[i]);
        o_vz[i] = inv * (s * (txz_x + tzz_z) + omc * fvz[i]);
    }
    *(float4*)(y_vx + base) = make_float4(o_vx[0], o_vx[1], o_vx[2], o_vx[3]);
    *(float4*)(y_vz + base) = make_float4(o_vz[0], o_vz[1], o_vz[2], o_vz[3]);
}

extern "C" void kernel_launch(void* const* d_in, const int* in_sizes, int n_in,
                              void* d_out, int out_size, void* d_ws, size_t ws_size,
                              hipStream_t stream) {
    const float* vp  = (const float*)d_in[0];
    const float* vs  = (const float*)d_in[1];
    const float* rho = (const float*)d_in[2];
    const float* vx  = (const float*)d_in[3];
    const float* vz  = (const float*)d_in[4];
    const float* txx = (const float*)d_in[5];
    const float* tzz = (const float*)d_in[6];
    const float* txz = (const float*)d_in[7];
    const float* dtp = (const float*)d_in[8];
    const float* hp  = (const float*)d_in[9];
    const float* dpm = (const float*)d_in[10];

    float* out   = (float*)d_out;
    float* y_vx  = out;
    float* y_vz  = out + (size_t)NPTS;
    float* y_txx = out + 2 * (size_t)NPTS;
    float* y_tzz = out + 3 * (size_t)NPTS;
    float* y_txz = out + 4 * (size_t)NPTS;

    dim3 block(256);
    dim3 grid(NQTOT / 256);
    stress_kernel<<<grid, block, 0, stream>>>(vp, vs, rho, vx, vz, txx, tzz, txz,
                                              dtp, hp, dpm, y_txx, y_tzz, y_txz);
    vel_kernel<<<grid, block, 0, stream>>>(rho, vx, vz, y_txx, y_tzz, y_txz,
                                           dtp, hp, dpm, y_vx, y_vz);
}

// Round 2
// 34.908 us; speedup vs baseline: 1.8462x; 1.8462x over previous
//
#include <hip/hip_runtime.h>

// Fused elastic wave time step (seistorch), B=4, NZ=NX=1024, f32.
// One block = one full x-row (256 threads x float4 = 1024 = NX), marching an
// R-row strip in z. Stress rows are computed into a 2-slot rolling LDS buffer
// and consumed by the velocity update of the same row (needs stress rows r and
// r-1), so the fresh stresses are never re-read from global memory.
// Circular-roll wrap via &(N-1).

constexpr int Bn = 4, NZ = 1024, NX = 1024;
constexpr int PLANE = NZ * NX;
constexpr int NPTS = Bn * PLANE;
constexpr int R = 8;                 // rows per strip
constexpr int NSTRIP = NZ / R;       // 128
constexpr int LOG_NSTRIP = 7;

__global__ __launch_bounds__(256, 2) void fused_wave_kernel(
    const float* __restrict__ vp, const float* __restrict__ vs,
    const float* __restrict__ rho, const float* __restrict__ vx,
    const float* __restrict__ vz, const float* __restrict__ txx,
    const float* __restrict__ tzz, const float* __restrict__ txz,
    const float* __restrict__ dtp, const float* __restrict__ hp,
    const float* __restrict__ dpml,
    float* __restrict__ y_vx, float* __restrict__ y_vz,
    float* __restrict__ y_txx, float* __restrict__ y_tzz,
    float* __restrict__ y_txz)
{
    __shared__ float s_txx[2][NX];
    __shared__ float s_tzz[2][NX];
    __shared__ float s_txz[2][NX];

    const int tid = threadIdx.x;
    const int x0 = tid * 4;
    const int xm1 = (x0 - 1) & (NX - 1);
    const int xp4 = (x0 + 4) & (NX - 1);
    const int strip = blockIdx.x & (NSTRIP - 1);
    const int b = blockIdx.x >> LOG_NSTRIP;
    const int z0 = strip * R;
    const size_t fb = (size_t)b * PLANE;

    const float dt = dtp[0], h = hp[0];
    const float dth = dt / h;

    // rolling registers: vx/vz of row r (start at r = z0-1)
    {
        const int rm = (z0 - 1) & (NZ - 1);
        // loaded below as the k=0 "current row" via the prologue
    }
    const int rm0 = (z0 - 1) & (NZ - 1);
    float4 vxr = *(const float4*)(vx + fb + (size_t)rm0 * NX + x0);
    float4 vzr = *(const float4*)(vz + fb + (size_t)rm0 * NX + x0);

    for (int k = 0; k <= R; ++k) {
        const int r  = (z0 - 1 + k) & (NZ - 1);
        const int rp = (r + 1) & (NZ - 1);
        const size_t rowb  = fb + (size_t)r * NX;
        const size_t rowbp = fb + (size_t)rp * NX;
        const int mrow = r * NX;

        float4 vxr1 = *(const float4*)(vx + rowbp + x0);
        float4 vzr1 = *(const float4*)(vz + rowbp + x0);
        float  vxm  = vx[rowb + xm1];
        float  vzp  = vz[rowb + xp4];
        float4 txxo = *(const float4*)(txx + rowb + x0);
        float4 tzzo = *(const float4*)(tzz + rowb + x0);
        float4 txzo = *(const float4*)(txz + rowb + x0);
        float4 vpv  = *(const float4*)(vp + mrow + x0);
        float4 vsv  = *(const float4*)(vs + mrow + x0);
        float4 rhv  = *(const float4*)(rho + mrow + x0);
        float4 dv   = *(const float4*)(dpml + mrow + x0);

        float fvx[5]  = {vxm, vxr.x, vxr.y, vxr.z, vxr.w};
        float fvz[5]  = {vzr.x, vzr.y, vzr.z, vzr.w, vzp};
        float fvx1[4] = {vxr1.x, vxr1.y, vxr1.z, vxr1.w};
        float fvz1[4] = {vzr1.x, vzr1.y, vzr1.z, vzr1.w};
        float ftxxo[4] = {txxo.x, txxo.y, txxo.z, txxo.w};
        float ftzzo[4] = {tzzo.x, tzzo.y, tzzo.z, tzzo.w};
        float ftxzo[4] = {txzo.x, txzo.y, txzo.z, txzo.w};
        float fvp[4] = {vpv.x, vpv.y, vpv.z, vpv.w};
        float fvs[4] = {vsv.x, vsv.y, vsv.z, vsv.w};
        float frh[4] = {rhv.x, rhv.y, rhv.z, rhv.w};
        float fd[4]  = {dv.x, dv.y, dv.z, dv.w};

        float o_txx[4], o_tzz[4], o_txz[4], inv[4], omc[4];
#pragma unroll
        for (int i = 0; i < 4; ++i) {
            float lam = frh[i] * (fvp[i] * fvp[i] - 2.0f * fvs[i] * fvs[i]);
            float mu  = frh[i] * fvs[i] * fvs[i];
            float vx_x = fvx[i + 1] - fvx[i];     // vx[x] - vx[x-1]
            float vz_z = fvz1[i] - fvz[i];        // vz[z+1] - vz[z]
            float vx_z = fvx1[i] - fvx[i + 1];    // vx[z+1] - vx[z]
            float vz_x = fvz[i + 1] - fvz[i];     // vz[x+1] - vz[x]
            float c = 0.5f * dt * fd[i];
            inv[i] = 1.0f / (1.0f + c);
            omc[i] = 1.0f - c;
            float lp2m = lam + 2.0f * mu;
            o_txx[i] = inv[i] * (dth * (lp2m * vx_x + lam * vz_z) + omc[i] * ftxxo[i]);
            o_tzz[i] = inv[i] * (dth * (lp2m * vz_z + lam * vx_x) + omc[i] * ftzzo[i]);
            o_txz[i] = inv[i] * (dth * mu * (vz_x + vx_z) + omc[i] * ftxzo[i]);
        }

        const int slot = k & 1;
        *(float4*)&s_txx[slot][x0] = make_float4(o_txx[0], o_txx[1], o_txx[2], o_txx[3]);
        *(float4*)&s_tzz[slot][x0] = make_float4(o_tzz[0], o_tzz[1], o_tzz[2], o_tzz[3]);
        *(float4*)&s_txz[slot][x0] = make_float4(o_txz[0], o_txz[1], o_txz[2], o_txz[3]);
        if (k > 0) {
            *(float4*)(y_txx + rowb + x0) = make_float4(o_txx[0], o_txx[1], o_txx[2], o_txx[3]);
            *(float4*)(y_tzz + rowb + x0) = make_float4(o_tzz[0], o_tzz[1], o_tzz[2], o_tzz[3]);
            *(float4*)(y_txz + rowb + x0) = make_float4(o_txz[0], o_txz[1], o_txz[2], o_txz[3]);
        }
        __syncthreads();

        if (k > 0) {
            // velocity row r: stress row r in regs/LDS slot, row r-1 in slot^1
            float  txxp4v = s_txx[slot][xp4];
            float  txzm1v = s_txz[slot][xm1];
            float4 txzzm = *(const float4*)&s_txz[slot ^ 1][x0];
            float4 tzzzm = *(const float4*)&s_tzz[slot ^ 1][x0];

            float ftxx5[5] = {o_txx[0], o_txx[1], o_txx[2], o_txx[3], txxp4v};
            float ftxz5[5] = {txzm1v, o_txz[0], o_txz[1], o_txz[2], o_txz[3]};
            float ftxzzm[4] = {txzzm.x, txzzm.y, txzzm.z, txzzm.w};
            float ftzzzm[4] = {tzzzm.x, tzzzm.y, tzzzm.z, tzzzm.w};
            float fvxc[4] = {vxr.x, vxr.y, vxr.z, vxr.w};
            float fvzc[4] = {vzr.x, vzr.y, vzr.z, vzr.w};

            float o_vx[4], o_vz[4];
#pragma unroll
            for (int i = 0; i < 4; ++i) {
                float txx_x = ftxx5[i + 1] - ftxx5[i];   // txx[x+1]-txx[x]
                float txz_z = ftxz5[i + 1] - ftxzzm[i];  // txz[z]-txz[z-1]
                float tzz_z = o_tzz[i] - ftzzzm[i];      // tzz[z]-tzz[z-1]
                float txz_x = ftxz5[i + 1] - ftxz5[i];   // txz[x]-txz[x-1]
                float s = dth / frh[i];
                o_vx[i] = inv[i] * (s * (txx_x + txz_z) + omc[i] * fvxc[i]);
                o_vz[i] = inv[i] * (s * (txz_x + tzz_z) + omc[i] * fvzc[i]);
            }
            *(float4*)(y_vx + rowb + x0) = make_float4(o_vx[0], o_vx[1], o_vx[2], o_vx[3]);
            *(float4*)(y_vz + rowb + x0) = make_float4(o_vz[0], o_vz[1], o_vz[2], o_vz[3]);
        }
        __syncthreads();   // protect slot^1 before next iteration overwrites it

        vxr = vxr1;
        vzr = vzr1;
    }
}

extern "C" void kernel_launch(void* const* d_in, const int* in_sizes, int n_in,
                              void* d_out, int out_size, void* d_ws, size_t ws_size,
                              hipStream_t stream) {
    const float* vp  = (const float*)d_in[0];
    const float* vs  = (const float*)d_in[1];
    const float* rho = (const float*)d_in[2];
    const float* vx  = (const float*)d_in[3];
    const float* vz  = (const float*)d_in[4];
    const float* txx = (const float*)d_in[5];
    const float* tzz = (const float*)d_in[6];
    const float* txz = (const float*)d_in[7];
    const float* dtp = (const float*)d_in[8];
    const float* hp  = (const float*)d_in[9];
    const float* dpm = (const float*)d_in[10];

    float* out   = (float*)d_out;
    float* y_vx  = out;
    float* y_vz  = out + (size_t)NPTS;
    float* y_txx = out + 2 * (size_t)NPTS;
    float* y_tzz = out + 3 * (size_t)NPTS;
    float* y_txz = out + 4 * (size_t)NPTS;

    dim3 block(256);
    dim3 grid(Bn * NSTRIP);   // 512 blocks, 2 per CU
    fused_wave_kernel<<<grid, block, 0, stream>>>(vp, vs, rho, vx, vz, txx, tzz, txz,
                                                  dtp, hp, dpm,
                                                  y_vx, y_vz, y_txx, y_tzz, y_txz);
}